// Round 3
// baseline (3582.252 us; speedup 1.0000x reference)
//
#include <hip/hip_runtime.h>
#include <hip/hip_fp16.h>

// N=1024 batch, H=1024 hidden, L=96 steps, 4H=4096 gate cols, K=H=1024.
#define LSTEPS 96
#define BN_EPS 1e-5f

typedef _Float16 f16;
typedef _Float16 f16x8 __attribute__((ext_vector_type(8)));
typedef float f32x4 __attribute__((ext_vector_type(4)));
typedef float f32x16 __attribute__((ext_vector_type(16)));

#define GLOAD_LDS16(gp, lp) __builtin_amdgcn_global_load_lds( \
    (const __attribute__((address_space(1))) void*)(gp),      \
    (__attribute__((address_space(3))) void*)(lp), 16, 0, 0)

__device__ __forceinline__ float sigf(float x) { return 1.f / (1.f + __expf(-x)); }
__device__ __forceinline__ float tanhfast(float x) {
  float e = __expf(2.f * x);
  return 1.f - 2.f / (e + 1.f);   // saturates correctly at +-inf
}

// ---------------------------------------------------------------------------
// Fragment layouts (mfma_f32_32x32x16_f16):
//   A (h, 1024x1024): frag(r32 = row>>5, k16 = k>>4); lane = (row&31)|((k>>3&1)<<5),
//     elem = k&7; frag = 512 f16 = 1KB contiguous.
//   W' (gate-interleaved): col32 = cb*4+g (cb channel-block, g gate); same rule.
// ---------------------------------------------------------------------------
__global__ __launch_bounds__(256) void prep_kernel(
    const float* __restrict__ W, const float* __restrict__ hin,
    const float* __restrict__ bih, const float* __restrict__ bhh,
    f16* __restrict__ Wfrag, f16* __restrict__ Afrag,
    float* __restrict__ bias, float* __restrict__ ssum, float* __restrict__ ssq,
    unsigned* __restrict__ ctr) {
  const int t0 = blockIdx.x * 256 + threadIdx.x;
  const int stride = gridDim.x * 256;
  for (int t = t0; t < 524288; t += stride) {          // W -> f16 frag order
    int lane = t & 63, frag = t >> 6;
    int col32 = frag >> 6, k16 = frag & 63;
    int g = col32 & 3, cb = col32 >> 2;
    int m = g * 1024 + cb * 32 + (lane & 31);
    int k0 = k16 * 16 + (lane >> 5) * 8;
    const float* src = W + (size_t)m * 1024 + k0;
    f16x8 v;
#pragma unroll
    for (int e = 0; e < 8; ++e) v[e] = (f16)src[e];
    *(f16x8*)(Wfrag + (size_t)t * 8) = v;
  }
  for (int t = t0; t < 131072; t += stride) {          // h0 -> f16 frag order
    int lane = t & 63, frag = t >> 6;
    int r32 = frag >> 6, k16 = frag & 63;
    int row = r32 * 32 + (lane & 31);
    int k0 = k16 * 16 + (lane >> 5) * 8;
    const float* src = hin + (size_t)row * 1024 + k0;
    f16x8 v;
#pragma unroll
    for (int e = 0; e < 8; ++e) v[e] = (f16)src[e];
    *(f16x8*)(Afrag + (size_t)t * 8) = v;
  }
  for (int t = t0; t < 4096; t += stride) {
    int g = (t >> 5) & 3, cb = t >> 7, j = t & 31;
    bias[t] = bih[g * 1024 + cb * 32 + j] + bhh[g * 1024 + cb * 32 + j];
  }
  for (int t = t0; t < 1024; t += stride) { ssum[t] = 0.f; ssq[t] = 0.f; }
  for (int t = t0; t < 128; t += stride) ctr[t] = 0u;
}

// ---------------------------------------------------------------------------
// Persistent kernel: all 96 steps. Grid 256 blocks (1/CU), 256 threads.
// Block (bg,cb): rows bg*128..+127, channels cb*32..+31 (x4 gates).
// Inter-step dep: block(bg,cb) reads A-frags written by blocks (bg,*) ->
// 32-block group barrier per bg via release/acquire agent atomics.
__global__ __launch_bounds__(256, 1) void lstm_persist(
    const f16* __restrict__ Wfrag, const float* __restrict__ bias,
    f16* __restrict__ Af0, f16* __restrict__ Af1, f16* __restrict__ stage,
    float* __restrict__ ssum, float* __restrict__ ssq,
    unsigned* __restrict__ ctrbase) {
  __shared__ alignas(16) f16 As[2 * 16 * 512];
  __shared__ alignas(16) f16 Bs[2 * 16 * 512];
  __shared__ alignas(16) f16 hl[128 * 40];
  __shared__ float frs[32], frq[32];
  const int tid = threadIdx.x, lane = tid & 63, wv = tid >> 6;
  const int bid = blockIdx.x;
  const int cb = (bid & 7) * 4 + ((bid >> 3) & 3);   // XCD-local W working set
  const int bg = bid >> 5;
  const int jl = lane & 31;
  const int rl4 = 4 * (lane >> 5);
  unsigned* ctr = ctrbase + bg * 16;                 // 64B-spaced counters

  const f16* Wg = Wfrag + (size_t)(cb * 4) * 64 * 512 + lane * 8;
  float bi[4];
#pragma unroll
  for (int g = 0; g < 4; ++g) bi[g] = bias[cb * 128 + g * 32 + jl];

  float creg[16];
#pragma unroll
  for (int q = 0; q < 16; ++q) creg[q] = 0.f;
  float s = 0.f, s2 = 0.f;

#define STAGE(B, KT)                                                   \
  {                                                                    \
    _Pragma("unroll")                                                  \
    for (int r = 0; r < 4; ++r) {                                      \
      GLOAD_LDS16(Ag + ((size_t)r * 64 + (KT) * 4 + wv) * 512,         \
                  &As[((B) * 16 + r * 4 + wv) * 512 + lane * 8]);      \
      GLOAD_LDS16(Wg + ((size_t)r * 64 + (KT) * 4 + wv) * 512,         \
                  &Bs[((B) * 16 + r * 4 + wv) * 512 + lane * 8]);      \
    }                                                                  \
  }

  for (int l = 0; l < LSTEPS; ++l) {
    const f16* Ab = (l & 1) ? Af1 : Af0;
    f16* An = (l & 1) ? Af0 : Af1;
    const f16* Ag = Ab + (size_t)(bg * 4) * 64 * 512 + lane * 8;

    f32x16 acc[4] = {};
    STAGE(0, 0);
    __syncthreads();
    int buf = 0;
    for (int kt = 0; kt < 16; ++kt) {
      if (kt < 15) STAGE(buf ^ 1, kt + 1);
#pragma unroll
      for (int kk = 0; kk < 4; ++kk) {
        f16x8 a = *(const f16x8*)&As[(buf * 16 + wv * 4 + kk) * 512 + lane * 8];
#pragma unroll
        for (int g = 0; g < 4; ++g) {
          f16x8 b = *(const f16x8*)&Bs[(buf * 16 + g * 4 + kk) * 512 + lane * 8];
          acc[g] = __builtin_amdgcn_mfma_f32_32x32x16_f16(a, b, acc[g], 0, 0, 0);
        }
      }
      __syncthreads();
      buf ^= 1;
    }

    // epilogue: C/D row = (reg&3)+8*(reg>>2)+4*(lane>>5), col = lane&31
    float hv[16];
#pragma unroll
    for (int reg = 0; reg < 16; ++reg) {
      float xi = acc[0][reg] + bi[0];
      float xf = acc[1][reg] + bi[1];
      float xg = acc[2][reg] + bi[2];
      float xo = acc[3][reg] + bi[3];
      float cn = sigf(xf) * creg[reg] + sigf(xi) * tanhfast(xg);
      creg[reg] = cn;
      float h = sigf(xo) * tanhfast(cn);
      hv[reg] = h;
      s += h; s2 += h * h;
    }

    // stage write (f16, [l][n][j], coalesced 64B per half-wave)
    f16* stp = stage + (size_t)l * 1048576 +
               (size_t)(bg * 128 + wv * 32) * 1024 + cb * 32 + jl;
#pragma unroll
    for (int reg = 0; reg < 16; ++reg) {
      int row_local = (reg & 3) + 8 * (reg >> 2) + rl4;
      stp[(size_t)row_local * 1024] = (f16)hv[reg];
      hl[(wv * 32 + row_local) * 40 + jl] = (f16)hv[reg];
    }

    if (l < LSTEPS - 1) {
      __syncthreads();
      // emit h fragments for next step's A
      {
        const int row_l = lane & 31, e0 = (lane >> 5) * 8;
#pragma unroll
        for (int kh = 0; kh < 2; ++kh) {
          f16x8 v = *(const f16x8*)&hl[(wv * 32 + row_l) * 40 + kh * 16 + e0];
          size_t fg = (size_t)((bg * 4 + wv) * 64 + cb * 2 + kh);
          *(f16x8*)(An + fg * 512 + lane * 8) = v;
        }
      }
      // group barrier: 32 blocks sharing bg
      __syncthreads();   // drains vmcnt: all waves' An stores complete at L2
      if (tid == 0) {
        __hip_atomic_fetch_add(ctr, 1u, __ATOMIC_RELEASE, __HIP_MEMORY_SCOPE_AGENT);
        unsigned tgt = 32u * (unsigned)(l + 1);
        while (__hip_atomic_load(ctr, __ATOMIC_ACQUIRE, __HIP_MEMORY_SCOPE_AGENT) < tgt)
          __builtin_amdgcn_s_sleep(1);
      }
      __syncthreads();
    }
  }
#undef STAGE

  // BN partial sums: thread's 16 rows all share channel cb*32+jl
  if (tid < 32) { frs[tid] = 0.f; frq[tid] = 0.f; }
  __syncthreads();
  atomicAdd(&frs[jl], s);
  atomicAdd(&frq[jl], s2);
  __syncthreads();
  if (tid < 32) {
    atomicAdd(&ssum[cb * 32 + tid], frs[tid]);
    atomicAdd(&ssq[cb * 32 + tid], frq[tid]);
  }
}

// ---------------------------------------------------------------------------
__global__ __launch_bounds__(256) void bn_finalize(
    const float* __restrict__ ssum, const float* __restrict__ ssq,
    const float* __restrict__ gamma, const float* __restrict__ beta,
    float* __restrict__ stat2) {
  int j = blockIdx.x * 256 + threadIdx.x;
  const float inv = 1.f / 98304.f;   // N*L
  float mean = ssum[j] * inv;
  float var = ssq[j] * inv - mean * mean;
  float sc = gamma[j] * rsqrtf(var + BN_EPS);
  stat2[2 * j] = sc;
  stat2[2 * j + 1] = beta[j] - mean * sc;
}

// Fused transpose + normalize: out[n][j][l] = stage[l][n][j]*sc[j]+sh[j].
__global__ __launch_bounds__(256) void trans_bn(
    const f16* __restrict__ stage, const float* __restrict__ stat2,
    float* __restrict__ out) {
  const int j = (blockIdx.x & 3) * 256 + threadIdx.x;
  const int n = blockIdx.x >> 2;
  const float sc = stat2[2 * j], sh = stat2[2 * j + 1];
  const f16* sp = stage + (size_t)n * 1024 + j;
  float* op = out + ((size_t)n * 1024 + j) * 96;
#pragma unroll
  for (int q = 0; q < 24; ++q) {
    f32x4 v;
#pragma unroll
    for (int e = 0; e < 4; ++e)
      v[e] = (float)sp[(size_t)(q * 4 + e) * 1048576] * sc + sh;
    ((f32x4*)op)[q] = v;
  }
}

// ---------------------------------------------------------------------------
// ws layout (bytes):
//   Wfrag f16   8,388,608 @ 0
//   Af0   f16   2,097,152 @  8,388,608
//   Af1   f16   2,097,152 @ 10,485,760
//   bias  f32      16,384 @ 12,582,912
//   ssum  f32       4,096 @ 12,599,296
//   ssq   f32       4,096 @ 12,603,392
//   stat2 f32       8,192 @ 12,607,488
//   ctr   u32         512 @ 12,615,680
//   stage f16 201,326,592 @ 16,777,216   (96 slots of [1024][1024])
// total ~208 MB
extern "C" void kernel_launch(void* const* d_in, const int* in_sizes, int n_in,
                              void* d_out, int out_size, void* d_ws, size_t ws_size,
                              hipStream_t stream) {
  const float* h_in  = (const float*)d_in[0];
  const float* W     = (const float*)d_in[1];
  const float* bih   = (const float*)d_in[2];
  const float* bhh   = (const float*)d_in[3];
  const float* gamma = (const float*)d_in[4];
  const float* beta  = (const float*)d_in[5];
  float* out = (float*)d_out;

  char* ws = (char*)d_ws;
  f16*      Wfrag = (f16*)(ws + 0);
  f16*      Af0   = (f16*)(ws + 8388608);
  f16*      Af1   = (f16*)(ws + 10485760);
  float*    bias  = (float*)(ws + 12582912);
  float*    ssum  = (float*)(ws + 12599296);
  float*    ssq   = (float*)(ws + 12603392);
  float*    stat2 = (float*)(ws + 12607488);
  unsigned* ctr   = (unsigned*)(ws + 12615680);
  f16*      stage = (f16*)(ws + 16777216);

  prep_kernel<<<1024, 256, 0, stream>>>(W, h_in, bih, bhh, Wfrag, Af0,
                                        bias, ssum, ssq, ctr);
  lstm_persist<<<256, 256, 0, stream>>>(Wfrag, bias, Af0, Af1, stage,
                                        ssum, ssq, ctr);
  bn_finalize<<<4, 256, 0, stream>>>(ssum, ssq, gamma, beta, stat2);
  trans_bn<<<4096, 256, 0, stream>>>(stage, stat2, out);
}